// Round 1
// baseline (152.435 us; speedup 1.0000x reference)
//
#include <hip/hip_runtime.h>

// Problem: B=4, T=4096, E=1024, H=64.
// out = (idx@Wq+bq) @ M_b,  M_b = (1/32) * (idx@Wk+bk)^T (idx@Wv+bv)  per batch.
// (no softmax / no mask in the reference -> attention is linear -> rank-64)

typedef __attribute__((ext_vector_type(8))) short bf16x8;   // 8 bf16 = 4 VGPRs
typedef __attribute__((ext_vector_type(4))) float f32x4;    // MFMA C/D

#define MFMA16(a, b, c) __builtin_amdgcn_mfma_f32_16x16x32_bf16((a), (b), (c), 0, 0, 0)

__device__ __forceinline__ unsigned short f2bf(float f) {
    unsigned int u = __float_as_uint(f);
    u += 0x7fffu + ((u >> 16) & 1u);          // round-to-nearest-even
    return (unsigned short)(u >> 16);
}

__device__ __forceinline__ void load_lds16(const unsigned short* g, unsigned short* l) {
    // async global->LDS, 16B per lane; LDS dest = wave-uniform base + lane*16
    __builtin_amdgcn_global_load_lds(
        (const __attribute__((address_space(1))) unsigned int*)g,
        (__attribute__((address_space(3))) unsigned int*)l, 16, 0, 0);
}

// ---------------------------------------------------------------------------
// K0: WT[n][k] = W_{n/64}[k][n&63] as bf16, n in [0,192), k in [0,1024).
//     Scale 1/32 (= 1024^-0.5) folded into the Wk slice.
__global__ void prep(const float* __restrict__ Wq, const float* __restrict__ Wk,
                     const float* __restrict__ Wv, unsigned short* __restrict__ WT) {
    int i = blockIdx.x * 256 + threadIdx.x;   // 192*1024 = 49152*4 -> grid 768
    int n = i >> 10, k = i & 1023;
    int mm = n >> 6, h = n & 63;
    float v;
    if (mm == 0)      v = Wq[k * 64 + h];
    else if (mm == 1) v = Wk[k * 64 + h] * 0.03125f;
    else              v = Wv[k * 64 + h];
    WT[i] = f2bf(v);
}

// ---------------------------------------------------------------------------
// K1: fused QKV projection.  A (idx rows) fragments straight from global fp32
// (each 128B line consumed exactly once); B tile (32k x 192n) double-buffered
// in LDS via global_load_lds.  Q stored [r][h] bf16; K,V stored transposed
// [b][h][t] bf16 (K pre-scaled by 1/32 via WT/bias).
__global__ __launch_bounds__(256) void qkv(
    const float* __restrict__ idx, const unsigned short* __restrict__ WT,
    const float* __restrict__ bq, const float* __restrict__ bk, const float* __restrict__ bv,
    unsigned short* __restrict__ Q, unsigned short* __restrict__ Kt,
    unsigned short* __restrict__ Vt) {
    __shared__ unsigned short Bt[2][192 * 32];      // 12 KB per buffer, no pad
    const int tid  = threadIdx.x;
    const int lane = tid & 63, wave = tid >> 6;
    const int r0 = blockIdx.x * 64;                 // 64 token rows per block

    auto stage_B = [&](int buf, int k0) {
        #pragma unroll
        for (int c = 0; c < 3; c++) {
            int grp   = wave * 3 + c;               // 12 groups of 64 chunks
            int chunk = grp * 64 + lane;
            int n = chunk >> 2, koff = (chunk & 3) * 8;
            load_lds16(WT + n * 1024 + k0 + koff, &Bt[buf][grp * 512]);
        }
    };

    const float* arow = idx + (size_t)(r0 + 16 * wave + (lane & 15)) * 1024
                        + ((lane >> 4) * 8);

    stage_B(0, 0);
    float4 f0 = *(const float4*)(arow);
    float4 f1 = *(const float4*)(arow + 4);

    const f32x4 z4 = {0.f, 0.f, 0.f, 0.f};
    f32x4 acc[12];
    #pragma unroll
    for (int i = 0; i < 12; i++) acc[i] = z4;

    for (int i = 0; i < 32; i++) {
        __syncthreads();                            // drains vmcnt: buf[i&1] + A regs ready
        if (i < 31) stage_B((i + 1) & 1, (i + 1) * 32);
        float4 nf0 = f0, nf1 = f1;
        if (i < 31) {                               // prefetch next A (hidden behind MFMAs)
            nf0 = *(const float4*)(arow + (i + 1) * 32);
            nf1 = *(const float4*)(arow + (i + 1) * 32 + 4);
        }
        bf16x8 a;
        a[0] = (short)f2bf(f0.x); a[1] = (short)f2bf(f0.y);
        a[2] = (short)f2bf(f0.z); a[3] = (short)f2bf(f0.w);
        a[4] = (short)f2bf(f1.x); a[5] = (short)f2bf(f1.y);
        a[6] = (short)f2bf(f1.z); a[7] = (short)f2bf(f1.w);
        const unsigned short* B = Bt[i & 1];
        #pragma unroll
        for (int nt = 0; nt < 12; nt++) {
            bf16x8 bb = *(const bf16x8*)&B[(nt * 16 + (lane & 15)) * 32 + ((lane >> 4) * 8)];
            acc[nt] = MFMA16(a, bb, acc[nt]);
        }
        f0 = nf0; f1 = nf1;
    }

    // epilogue: C/D layout col=lane&15, row=(lane>>4)*4+reg
    const int rbase = r0 + 16 * wave + (lane >> 4) * 4;
    #pragma unroll
    for (int nt = 0; nt < 12; nt++) {
        int m = nt >> 2;                            // 0=Q 1=K 2=V
        int h = (nt & 3) * 16 + (lane & 15);
        float bias = (m == 0) ? bq[h] : (m == 1) ? bk[h] * 0.03125f : bv[h];
        #pragma unroll
        for (int reg = 0; reg < 4; reg++) {
            int r = rbase + reg;
            unsigned short v = f2bf(acc[nt][reg] + bias);
            if (m == 0) {
                Q[r * 64 + h] = v;
            } else {
                int b = r >> 12, t = r & 4095;
                unsigned short* dst = (m == 1) ? Kt : Vt;
                dst[b * 262144 + h * 4096 + t] = v;
            }
        }
    }
}

// ---------------------------------------------------------------------------
// K2: partial M: part[b][c] = Kt[b][:, c*512:(c+1)*512] @ Vt[b][:, ...]^T
//     A (=K^T) and B (=V) fragments contiguous straight from global bf16.
__global__ __launch_bounds__(256) void ktv_partial(
    const unsigned short* __restrict__ Kt, const unsigned short* __restrict__ Vt,
    float* __restrict__ part) {
    const int lane = threadIdx.x & 63, wave = threadIdx.x >> 6;
    const int c = blockIdx.x, b = blockIdx.y;
    const unsigned short* Kb = Kt + b * 262144;
    const unsigned short* Vb = Vt + b * 262144;
    const f32x4 z4 = {0.f, 0.f, 0.f, 0.f};
    f32x4 acc[4] = {z4, z4, z4, z4};
    const int m  = 16 * wave + (lane & 15);
    const int tq = (lane >> 4) * 8;
    #pragma unroll 4
    for (int it = 0; it < 16; it++) {
        int t0 = c * 512 + it * 32 + tq;
        bf16x8 a = *(const bf16x8*)&Kb[m * 4096 + t0];
        #pragma unroll
        for (int nt = 0; nt < 4; nt++) {
            bf16x8 bb = *(const bf16x8*)&Vb[(nt * 16 + (lane & 15)) * 4096 + t0];
            acc[nt] = MFMA16(a, bb, acc[nt]);
        }
    }
    float* P = part + (b * 8 + c) * 4096;
    const int rowb = 16 * wave + (lane >> 4) * 4;
    #pragma unroll
    for (int nt = 0; nt < 4; nt++)
        #pragma unroll
        for (int reg = 0; reg < 4; reg++)
            P[(rowb + reg) * 64 + nt * 16 + (lane & 15)] = acc[nt][reg];
}

// ---------------------------------------------------------------------------
// K3: M reduce over 8 chunks; store TRANSPOSED bf16: Mt[b][h2][h1]
//     (ready to be the MFMA B-operand of K4; scale already folded into K).
__global__ void reduce_m(const float* __restrict__ part, unsigned short* __restrict__ Mt) {
    int i = blockIdx.x * 256 + threadIdx.x;         // 4*64*64 = 16384 -> grid 64
    int b = i >> 12, h1 = (i >> 6) & 63, h2 = i & 63;
    float s = 0.f;
    #pragma unroll
    for (int cc = 0; cc < 8; cc++) s += part[(b * 8 + cc) * 4096 + h1 * 64 + h2];
    Mt[b * 4096 + h2 * 64 + h1] = f2bf(s);
}

// ---------------------------------------------------------------------------
// K4: out[r][h2] = Q[r][:] @ M_b[:, h2], fp32 out.
__global__ __launch_bounds__(256) void qm(
    const unsigned short* __restrict__ Q, const unsigned short* __restrict__ Mt,
    float* __restrict__ out) {
    const int lane = threadIdx.x & 63, wave = threadIdx.x >> 6;
    const int r0 = blockIdx.x * 64;
    const int b  = r0 >> 12;
    const f32x4 z4 = {0.f, 0.f, 0.f, 0.f};
    f32x4 acc[4] = {z4, z4, z4, z4};
    const int rr = r0 + 16 * wave + (lane & 15);
    const int kq = (lane >> 4) * 8;
    #pragma unroll
    for (int ks = 0; ks < 2; ks++) {
        int k0 = ks * 32;
        bf16x8 a = *(const bf16x8*)&Q[rr * 64 + k0 + kq];
        #pragma unroll
        for (int nt = 0; nt < 4; nt++) {
            bf16x8 bb = *(const bf16x8*)&Mt[b * 4096 + (nt * 16 + (lane & 15)) * 64 + k0 + kq];
            acc[nt] = MFMA16(a, bb, acc[nt]);
        }
    }
    const int rowb = r0 + 16 * wave + (lane >> 4) * 4;
    #pragma unroll
    for (int nt = 0; nt < 4; nt++)
        #pragma unroll
        for (int reg = 0; reg < 4; reg++)
            out[(rowb + reg) * 64 + nt * 16 + (lane & 15)] = acc[nt][reg];
}

// ---------------------------------------------------------------------------
extern "C" void kernel_launch(void* const* d_in, const int* in_sizes, int n_in,
                              void* d_out, int out_size, void* d_ws, size_t ws_size,
                              hipStream_t stream) {
    const float* idx = (const float*)d_in[0];
    const float* Wq  = (const float*)d_in[1];
    const float* bq  = (const float*)d_in[2];
    const float* Wk  = (const float*)d_in[3];
    const float* bk  = (const float*)d_in[4];
    const float* Wv  = (const float*)d_in[5];
    const float* bv  = (const float*)d_in[6];
    float* out = (float*)d_out;

    char* ws = (char*)d_ws;
    unsigned short* WT = (unsigned short*)(ws);                        // 384 KB
    unsigned short* Q  = (unsigned short*)(ws + (512u  << 10));        // 2 MB
    unsigned short* Kt = (unsigned short*)(ws + (2560u << 10));        // 2 MB
    unsigned short* Vt = (unsigned short*)(ws + (4608u << 10));        // 2 MB
    float*          Pp = (float*)         (ws + (6656u << 10));        // 512 KB
    unsigned short* Mt = (unsigned short*)(ws + (7168u << 10));        // 32 KB

    hipLaunchKernelGGL(prep,        dim3(768),    dim3(256), 0, stream, Wq, Wk, Wv, WT);
    hipLaunchKernelGGL(qkv,         dim3(256),    dim3(256), 0, stream,
                       idx, WT, bq, bk, bv, Q, Kt, Vt);
    hipLaunchKernelGGL(ktv_partial, dim3(8, 4),   dim3(256), 0, stream, Kt, Vt, Pp);
    hipLaunchKernelGGL(reduce_m,    dim3(64),     dim3(256), 0, stream, Pp, Mt);
    hipLaunchKernelGGL(qm,          dim3(256),    dim3(256), 0, stream, Q, Mt, out);
}

// Round 3
// 133.177 us; speedup vs baseline: 1.1446x; 1.1446x over previous
//
#include <hip/hip_runtime.h>

// B=4, T=4096, E=1024, H=64.
// out = Q @ M_b,  M_b = (1/32) * K_b^T V_b,  Q/K/V = idx@W + b   (linear attention:
// reference applies no mask/softmax). Scale folded into Wk/bk.

typedef __attribute__((ext_vector_type(8))) short bf16x8;   // 8 bf16 = 4 VGPRs
typedef __attribute__((ext_vector_type(4))) float f32x4;    // MFMA C/D

#define MFMA16(a, b, c) __builtin_amdgcn_mfma_f32_16x16x32_bf16((a), (b), (c), 0, 0, 0)

__device__ __forceinline__ unsigned short f2bf(float f) {
    unsigned int u = __float_as_uint(f);
    u += 0x7fffu + ((u >> 16) & 1u);          // round-to-nearest-even
    return (unsigned short)(u >> 16);
}

// ---------------------------------------------------------------------------
// K0: weights -> MFMA-fragment order.
// Chunk index t = (k0i*12 + nt)*64 + lane holds 8 bf16:
//   W^T[n][k], n = nt*16 + (lane&15), k = k0i*32 + (lane>>4)*8 + j.
// n<64 -> Wq, n<128 -> Wk * 1/32, else Wv.   (W is [k][h] in memory)
__global__ void prep(const float* __restrict__ Wq, const float* __restrict__ Wk,
                     const float* __restrict__ Wv, unsigned short* __restrict__ WB) {
    int t = blockIdx.x * 256 + threadIdx.x;   // 96 blocks -> 24576 chunks
    int k0i = t / 768;
    int rem = t - k0i * 768;
    int nt = rem >> 6, lane = rem & 63;
    int n = nt * 16 + (lane & 15);
    int kb = k0i * 32 + ((lane >> 4) * 8);
    int mm = n >> 6, h = n & 63;
    const float* W = (mm == 0) ? Wq : (mm == 1) ? Wk : Wv;
    float sc = (mm == 1) ? 0.03125f : 1.0f;
    bf16x8 v;
    #pragma unroll
    for (int j = 0; j < 8; j++) v[j] = (short)f2bf(W[(size_t)(kb + j) * 64 + h] * sc);
    *(bf16x8*)(WB + (size_t)t * 8) = v;
}

// ---------------------------------------------------------------------------
// K1: fused QKV projection, LDS/barrier-free K-loop.
// Block = 32 rows x 4 K-split waves (K=256 each). Per wave: 2 m-tiles (M=32),
// 12 n-tiles, 8 K-iters. B fragments coalesced straight from WB (L2-hot).
// End: fp32 LDS reduction across the 4 K-split waves, wave 0 does epilogue.
__global__ __launch_bounds__(256, 2) void qkv(
    const float* __restrict__ idx, const unsigned short* __restrict__ WB,
    const float* __restrict__ bq, const float* __restrict__ bk, const float* __restrict__ bv,
    unsigned short* __restrict__ Q, unsigned short* __restrict__ Kt,
    unsigned short* __restrict__ Vt) {
    __shared__ float red[2][64][97];                // +1 pad: conflict-free
    const int lane = threadIdx.x & 63, kh = threadIdx.x >> 6;
    const int r0 = blockIdx.x * 32;

    const float* aLoP = idx + (size_t)(r0 + (lane & 15)) * 1024 + kh * 256 + ((lane >> 4) * 8);
    const float* aHiP = aLoP + 16 * 1024;

    const f32x4 z4 = {0.f, 0.f, 0.f, 0.f};
    f32x4 accLo[12], accHi[12];
    #pragma unroll
    for (int i = 0; i < 12; i++) { accLo[i] = z4; accHi[i] = z4; }

    float4 c0 = *(const float4*)(aLoP);
    float4 c1 = *(const float4*)(aLoP + 4);
    float4 c2 = *(const float4*)(aHiP);
    float4 c3 = *(const float4*)(aHiP + 4);

    #pragma unroll 2
    for (int i = 0; i < 8; i++) {
        float4 n0 = c0, n1 = c1, n2 = c2, n3 = c3;
        if (i < 7) {                               // 1-deep A prefetch (HBM stream)
            n0 = *(const float4*)(aLoP + (i + 1) * 32);
            n1 = *(const float4*)(aLoP + (i + 1) * 32 + 4);
            n2 = *(const float4*)(aHiP + (i + 1) * 32);
            n3 = *(const float4*)(aHiP + (i + 1) * 32 + 4);
        }
        // coalesced B fragments: lane-contiguous 16B, 1KB/instr, L2-hot
        const unsigned short* Bp = WB + (size_t)(((kh * 8 + i) * 12) * 64 + lane) * 8;
        bf16x8 bb[12];
        #pragma unroll
        for (int nt = 0; nt < 12; nt++) bb[nt] = *(const bf16x8*)(Bp + nt * 512);
        bf16x8 aL, aH;
        aL[0] = (short)f2bf(c0.x); aL[1] = (short)f2bf(c0.y);
        aL[2] = (short)f2bf(c0.z); aL[3] = (short)f2bf(c0.w);
        aL[4] = (short)f2bf(c1.x); aL[5] = (short)f2bf(c1.y);
        aL[6] = (short)f2bf(c1.z); aL[7] = (short)f2bf(c1.w);
        aH[0] = (short)f2bf(c2.x); aH[1] = (short)f2bf(c2.y);
        aH[2] = (short)f2bf(c2.z); aH[3] = (short)f2bf(c2.w);
        aH[4] = (short)f2bf(c3.x); aH[5] = (short)f2bf(c3.y);
        aH[6] = (short)f2bf(c3.z); aH[7] = (short)f2bf(c3.w);
        #pragma unroll
        for (int nt = 0; nt < 12; nt++) {
            accLo[nt] = MFMA16(aL, bb[nt], accLo[nt]);
            accHi[nt] = MFMA16(aH, bb[nt], accHi[nt]);
        }
        c0 = n0; c1 = n1; c2 = n2; c3 = n3;
    }

    // --- K-split reduction: final = (kh0+kh2) + (kh1+kh3) ---
    if (kh >= 2) {
        int buf = kh - 2;
        #pragma unroll
        for (int nt = 0; nt < 12; nt++)
            #pragma unroll
            for (int reg = 0; reg < 4; reg++) {
                red[buf][lane][nt * 4 + reg]      = accLo[nt][reg];
                red[buf][lane][48 + nt * 4 + reg] = accHi[nt][reg];
            }
    }
    __syncthreads();
    if (kh < 2) {
        #pragma unroll
        for (int nt = 0; nt < 12; nt++)
            #pragma unroll
            for (int reg = 0; reg < 4; reg++) {
                accLo[nt][reg] += red[kh][lane][nt * 4 + reg];
                accHi[nt][reg] += red[kh][lane][48 + nt * 4 + reg];
            }
    }
    __syncthreads();
    if (kh == 1) {
        #pragma unroll
        for (int nt = 0; nt < 12; nt++)
            #pragma unroll
            for (int reg = 0; reg < 4; reg++) {
                red[0][lane][nt * 4 + reg]      = accLo[nt][reg];
                red[0][lane][48 + nt * 4 + reg] = accHi[nt][reg];
            }
    }
    __syncthreads();
    if (kh == 0) {
        // epilogue: C/D layout col=lane&15, row=(lane>>4)*4+reg
        #pragma unroll
        for (int nt = 0; nt < 12; nt++) {
            int m = nt >> 2;                       // 0=Q 1=K 2=V
            int h = (nt & 3) * 16 + (lane & 15);
            float bias = (m == 0) ? bq[h] : (m == 1) ? bk[h] * 0.03125f : bv[h];
            #pragma unroll
            for (int rg = 0; rg < 2; rg++) {
                int rbase = r0 + rg * 16 + (lane >> 4) * 4;
                #pragma unroll
                for (int reg = 0; reg < 4; reg++) {
                    float s = (rg ? accHi[nt][reg] : accLo[nt][reg])
                              + red[0][lane][rg * 48 + nt * 4 + reg] + bias;
                    int r = rbase + reg;
                    unsigned short v = f2bf(s);
                    if (m == 0) {
                        Q[(size_t)r * 64 + h] = v;
                    } else {
                        int b = r >> 12, t = r & 4095;
                        unsigned short* dst = (m == 1) ? Kt : Vt;
                        dst[(size_t)b * 262144 + h * 4096 + t] = v;
                    }
                }
            }
        }
    }
}

// ---------------------------------------------------------------------------
// K2: partial M over 16 T-chunks of 256: part[b][c] = Kt_chunk @ Vt_chunk^T (fp32)
__global__ __launch_bounds__(256) void ktv_partial(
    const unsigned short* __restrict__ Kt, const unsigned short* __restrict__ Vt,
    float* __restrict__ part) {
    const int lane = threadIdx.x & 63, wave = threadIdx.x >> 6;
    const int c = blockIdx.x, b = blockIdx.y;
    const unsigned short* Kb = Kt + (size_t)b * 262144;
    const unsigned short* Vb = Vt + (size_t)b * 262144;
    const f32x4 z4 = {0.f, 0.f, 0.f, 0.f};
    f32x4 acc[4] = {z4, z4, z4, z4};
    const int m  = 16 * wave + (lane & 15);
    const int tq = (lane >> 4) * 8;
    #pragma unroll
    for (int it = 0; it < 8; it++) {
        int t0 = c * 256 + it * 32 + tq;
        bf16x8 a = *(const bf16x8*)&Kb[(size_t)m * 4096 + t0];
        #pragma unroll
        for (int nt = 0; nt < 4; nt++) {
            bf16x8 bb = *(const bf16x8*)&Vb[(size_t)(nt * 16 + (lane & 15)) * 4096 + t0];
            acc[nt] = MFMA16(a, bb, acc[nt]);
        }
    }
    float* P = part + (size_t)(b * 16 + c) * 4096;
    const int rowb = 16 * wave + (lane >> 4) * 4;
    #pragma unroll
    for (int nt = 0; nt < 4; nt++)
        #pragma unroll
        for (int reg = 0; reg < 4; reg++)
            P[(rowb + reg) * 64 + nt * 16 + (lane & 15)] = acc[nt][reg];
}

// ---------------------------------------------------------------------------
// K3: M reduce over 16 chunks; store TRANSPOSED bf16: Mt[b][h2][h1]
__global__ void reduce_m(const float* __restrict__ part,
                         unsigned short* __restrict__ Mt) {
    int i = blockIdx.x * 256 + threadIdx.x;         // 16384 -> grid 64
    int b = i >> 12, h1 = (i >> 6) & 63, h2 = i & 63;
    float s = 0.f;
    #pragma unroll
    for (int cc = 0; cc < 16; cc++)
        s += part[(size_t)(b * 16 + cc) * 4096 + h1 * 64 + h2];
    Mt[(size_t)b * 4096 + h2 * 64 + h1] = f2bf(s);
}

// ---------------------------------------------------------------------------
// K4: out[r][h2] = Q[r][:] @ M_b[:, h2], fp32 out.
__global__ __launch_bounds__(256) void qm(
    const unsigned short* __restrict__ Q, const unsigned short* __restrict__ Mt,
    float* __restrict__ out) {
    const int lane = threadIdx.x & 63, wave = threadIdx.x >> 6;
    const int r0 = blockIdx.x * 64;
    const int b  = r0 >> 12;
    const f32x4 z4 = {0.f, 0.f, 0.f, 0.f};
    f32x4 acc[4] = {z4, z4, z4, z4};
    const int rr = r0 + 16 * wave + (lane & 15);
    const int kq = (lane >> 4) * 8;
    #pragma unroll
    for (int ks = 0; ks < 2; ks++) {
        int k0 = ks * 32;
        bf16x8 a = *(const bf16x8*)&Q[(size_t)rr * 64 + k0 + kq];
        #pragma unroll
        for (int nt = 0; nt < 4; nt++) {
            bf16x8 bb = *(const bf16x8*)&Mt[(size_t)b * 4096 + (nt * 16 + (lane & 15)) * 64 + k0 + kq];
            acc[nt] = MFMA16(a, bb, acc[nt]);
        }
    }
    const int rowb = r0 + 16 * wave + (lane >> 4) * 4;
    #pragma unroll
    for (int nt = 0; nt < 4; nt++)
        #pragma unroll
        for (int reg = 0; reg < 4; reg++)
            out[(size_t)(rowb + reg) * 64 + nt * 16 + (lane & 15)] = acc[nt][reg];
}

// ---------------------------------------------------------------------------
// Workspace layout (no aliasing with live data):
//   [0, 384K)   WB   (dead after qkv)
//   [0, 1M)     Pp   (written by ktv_partial, AFTER qkv -> safe reuse of WB)
//   [1M, 3M)    Q
//   [3M, 5M)    Kt
//   [5M, 7M)    Vt
//   [7M, 7M+32K) Mt
extern "C" void kernel_launch(void* const* d_in, const int* in_sizes, int n_in,
                              void* d_out, int out_size, void* d_ws, size_t ws_size,
                              hipStream_t stream) {
    const float* idx = (const float*)d_in[0];
    const float* Wq  = (const float*)d_in[1];
    const float* bq  = (const float*)d_in[2];
    const float* Wk  = (const float*)d_in[3];
    const float* bk  = (const float*)d_in[4];
    const float* Wv  = (const float*)d_in[5];
    const float* bv  = (const float*)d_in[6];
    float* out = (float*)d_out;

    char* ws = (char*)d_ws;
    unsigned short* WB = (unsigned short*)(ws);
    float*          Pp = (float*)(ws);
    unsigned short* Q  = (unsigned short*)(ws + (1024u << 10));
    unsigned short* Kt = (unsigned short*)(ws + (3072u << 10));
    unsigned short* Vt = (unsigned short*)(ws + (5120u << 10));
    unsigned short* Mt = (unsigned short*)(ws + (7168u << 10));

    hipLaunchKernelGGL(prep,        dim3(96),     dim3(256), 0, stream, Wq, Wk, Wv, WB);
    hipLaunchKernelGGL(qkv,         dim3(512),    dim3(256), 0, stream,
                       idx, WB, bq, bk, bv, Q, Kt, Vt);
    hipLaunchKernelGGL(ktv_partial, dim3(16, 4),  dim3(256), 0, stream, Kt, Vt, Pp);
    hipLaunchKernelGGL(reduce_m,    dim3(64),     dim3(256), 0, stream, Pp, Mt);
    hipLaunchKernelGGL(qm,          dim3(256),    dim3(256), 0, stream, Q, Mt, out);
}